// Round 9
// baseline (175.221 us; speedup 1.0000x reference)
//
#include <hip/hip_runtime.h>
#include <hip/hip_bf16.h>
#include <math.h>

#define T_ 2048
#define C_ 1024
#define H_ 128
#define NB 8
#define WN 131072                 // 128*1024 per weight
#define SC 0.08838834764831845f   // 1/sqrt(128)

typedef __attribute__((ext_vector_type(8))) short bf16x8;
typedef __attribute__((ext_vector_type(8))) unsigned short u16x8;
typedef __attribute__((ext_vector_type(4))) float f32x4;

#define MFMA16(a,b,c) __builtin_amdgcn_mfma_f32_16x16x32_bf16((a),(b),(c),0,0,0)

__device__ __forceinline__ unsigned short f2bf(float f) {
    union { float f; unsigned u; } v; v.f = f;
    unsigned r = v.u + 0x7fffu + ((v.u >> 16) & 1u);
    return (unsigned short)(r >> 16);
}
__device__ __forceinline__ float bf2f(unsigned short u) {
    union { unsigned u; float f; } v; v.u = ((unsigned)u) << 16; return v.f;
}
__device__ __forceinline__ unsigned pk2bf(float a, float b) {
    __hip_bfloat162 h = __float22bfloat162_rn(float2{a, b});
    union { __hip_bfloat162 h; unsigned u; } v; v.h = h; return v.u;
}
// async global->LDS, 16B per lane; lds dest = uniform base + laneid*16
__device__ __forceinline__ void gld16(void* lds, const void* g) {
    __builtin_amdgcn_global_load_lds(
        (const __attribute__((address_space(1))) unsigned*)g,
        (__attribute__((address_space(3))) unsigned*)lds, 16, 0, 0);
}

// ---------- kernel 1: W fp32 -> bf16 (Wq pre-scaled by 1/sqrt(H)) ----------
__global__ __launch_bounds__(256) void wconv(const float* __restrict__ Wq,
                                             const float* __restrict__ Wk,
                                             const float* __restrict__ Wv,
                                             unsigned short* __restrict__ Wb) {
    int e = (blockIdx.x * 256 + threadIdx.x) * 8;       // < 393216
    int which = e >> 17;
    int off = e & (WN - 1);
    const float* src = (which == 0) ? Wq : (which == 1 ? Wk : Wv);
    float s = (which == 0) ? SC : 1.0f;
    const float4* p = (const float4*)(src + off);
    float4 a = p[0], b = p[1];
    uint4 o = { pk2bf(a.x * s, a.y * s), pk2bf(a.z * s, a.w * s),
                pk2bf(b.x * s, b.y * s), pk2bf(b.z * s, b.w * s) };
    *(uint4*)(Wb + e) = o;
}

// ---------- kernel 2: fused QKV projection (v5: 128x96 retile, 2x MFMA density) ----------
// grid 512 = 128 M-tiles x 4 N-splits of 96. Block 128(M)x96(N), BK=64,
// 16 K-steps, 4 waves (wave tile 64x48, acc[4][3] = 24 MFMA/interval on
// 14 ds_read_b128 -- bq reuse 4x). LDS 56 KB -> 2 blocks/CU. Same counted-vmcnt
// skeleton as R7 (proven): BAR waits vmcnt(8) = 3 W gld16 (oldest) land, the
// 8 x reg-loads stay in flight across the barrier (consumed ~1.5 iters later).
// Both-sides slot-XOR swizzle; all row bases %8==0 so read key = l16&7 matches.
__global__ __launch_bounds__(256, 2) void proj(const float* __restrict__ x,
                                               const unsigned short* __restrict__ Wb,
                                               unsigned short* __restrict__ Q,
                                               unsigned short* __restrict__ K,
                                               unsigned short* __restrict__ V) {
    __shared__ unsigned short Xs[2][128][64];   // 32 KB, swizzled slots
    __shared__ unsigned short Ws[2][96][64];    // 24 KB, swizzled slots

    const int tid  = threadIdx.x;
    const int wave = tid >> 6, lane = tid & 63;
    const int quad = lane >> 4, l16 = lane & 15;
    const int wm   = wave >> 1, wn = wave & 1;
    const int m0   = (blockIdx.x >> 2) * 128;
    const int n0   = (blockIdx.x & 3) * 96;

    f32x4 acc[4][3];
    #pragma unroll
    for (int i = 0; i < 4; i++)
        #pragma unroll
        for (int j = 0; j < 3; j++) acc[i][j] = {0.f, 0.f, 0.f, 0.f};

    // x: thread t -> row t>>1 (2 threads/row), 32 fp32 at col (t&1)*32
    const int xrow = tid >> 1, xch = tid & 1;
    const float* xg = x + (size_t)(m0 + xrow) * C_ + xch * 32;
    const int xk = xrow & 7;                                  // Xs swizzle key
    const int key = l16 & 7;                                  // read-side swizzle key
    // W: wave stages rows n0+wave*24..+23 (3 gld16 of 8 rows each);
    // source slot pre-swizzled: (lane&7) ^ (lane>>3)  [row&7 == lane>>3]
    const unsigned short* wg = Wb + (size_t)(n0 + wave * 24 + (lane >> 3)) * C_
                               + (size_t)(((lane & 7) ^ (lane >> 3)) * 8);

    float4 xA[8], xB[8];

    #define WISSUE(buf, kc) do {                                                  \
        _Pragma("unroll")                                                         \
        for (int i = 0; i < 3; i++)                                               \
            gld16(&Ws[buf][wave * 24 + i * 8][0], wg + (size_t)i * 8 * C_ + (kc));\
    } while (0)

    #define XLOAD(dst, kc) do {                                                   \
        const float* xp = xg + (kc);                                              \
        _Pragma("unroll")                                                         \
        for (int i = 0; i < 8; i++) dst[i] = *(const float4*)(xp + 4 * i);        \
    } while (0)

    #define XWR(buf, src) do {                                                    \
        _Pragma("unroll")                                                         \
        for (int j = 0; j < 4; j++) {                                             \
            uint4 u = { pk2bf(src[2*j].x,   src[2*j].y),                          \
                        pk2bf(src[2*j].z,   src[2*j].w),                          \
                        pk2bf(src[2*j+1].x, src[2*j+1].y),                        \
                        pk2bf(src[2*j+1].z, src[2*j+1].w) };                      \
            *(uint4*)&Xs[buf][xrow][((xch * 4 + j) ^ xk) * 8] = u;                \
        }                                                                         \
    } while (0)

    #define COMPUTE(buf) do {                                                     \
        bf16x8 af[4][2];                                                          \
        _Pragma("unroll")                                                         \
        for (int kk = 0; kk < 2; kk++)                                            \
            _Pragma("unroll")                                                     \
            for (int mf = 0; mf < 4; mf++)                                        \
                af[mf][kk] = *(bf16x8*)&Xs[buf][wm * 64 + mf * 16 + l16]          \
                                          [((kk * 4 + quad) ^ key) * 8];          \
        _Pragma("unroll")                                                         \
        for (int kk = 0; kk < 2; kk++)                                            \
            _Pragma("unroll")                                                     \
            for (int nf = 0; nf < 3; nf++) {                                      \
                bf16x8 bq = *(bf16x8*)&Ws[buf][wn * 48 + nf * 16 + l16]           \
                                         [((kk * 4 + quad) ^ key) * 8];           \
                _Pragma("unroll")                                                 \
                for (int mf = 0; mf < 4; mf++)                                    \
                    acc[mf][nf] = MFMA16(af[mf][kk], bq, acc[mf][nf]);            \
            }                                                                     \
    } while (0)

    // counted barrier: 3 W gld16 (oldest) must land; 8 x reg-loads stay in flight
    #define BAR8 do {                                                             \
        asm volatile("s_waitcnt vmcnt(8) lgkmcnt(0)" ::: "memory");               \
        __builtin_amdgcn_s_barrier();                                             \
        __builtin_amdgcn_sched_barrier(0);                                        \
    } while (0)
    #define BAR0 do {                                                             \
        asm volatile("s_waitcnt vmcnt(0) lgkmcnt(0)" ::: "memory");               \
        __builtin_amdgcn_s_barrier();                                             \
        __builtin_amdgcn_sched_barrier(0);                                        \
    } while (0)
    #define PIN __builtin_amdgcn_sched_barrier(0)

    // prologue: x(0), W(0), x(1); Xs[0] <- x(0)
    XLOAD(xA, 0);
    WISSUE(0, 0);
    PIN;
    XLOAD(xB, 64);
    XWR(0, xA);                       // auto vmcnt wait on xA

    // iters 0..13 as 7 pairs (parity -> compile-time reg-set/buf indices)
    for (int t = 0; t < 7; t++) {
        BAR8;                         // W(2t) landed; x(2t+1) still flying
        WISSUE(1, (2 * t + 1) * 64);
        PIN;                          // keep W older than x (vmcnt arithmetic)
        XLOAD(xA, (2 * t + 2) * 64);
        COMPUTE(0);
        XWR(1, xB);                   // Xs[1] <- x(2t+1)
        BAR8;
        WISSUE(0, (2 * t + 2) * 64);
        PIN;
        XLOAD(xB, (2 * t + 3) * 64);
        COMPUTE(1);
        XWR(0, xA);                   // Xs[0] <- x(2t+2)
    }
    // it=14 (buf 0): last W issue, no more x loads
    BAR8;
    WISSUE(1, 15 * 64);
    COMPUTE(0);
    XWR(1, xB);                       // Xs[1] <- x(15)
    // it=15 (buf 1): full drain
    BAR0;
    COMPUTE(1);

    #undef WISSUE
    #undef XLOAD
    #undef XWR
    #undef COMPUTE
    #undef BAR8
    #undef BAR0
    #undef PIN

    #pragma unroll
    for (int nf = 0; nf < 3; nf++) {
        int nb = n0 + wn * 48 + nf * 16;
        int which = nb >> 7;                   // frag-uniform (16-col frag never straddles)
        unsigned short* dst = (which == 0) ? Q : (which == 1 ? K : V);
        int c = (nb & 127) + l16;
        #pragma unroll
        for (int mf = 0; mf < 4; mf++)
            #pragma unroll
            for (int r = 0; r < 4; r++)
                dst[(size_t)(m0 + wm * 64 + mf * 16 + quad * 4 + r) * H_ + c] = f2bf(acc[mf][nf][r]);
    }
}

// ---------- kernel 3: split-K flash causal attention (v6: split width 512, unchanged) ----------
__global__ __launch_bounds__(256, 3) void attn(const unsigned short* __restrict__ Qg,
                                               const unsigned short* __restrict__ Kg,
                                               const unsigned short* __restrict__ Vg,
                                               unsigned short* __restrict__ Ob,
                                               float* __restrict__ Ml) {
    const int bid = blockIdx.x;
    const int b   = bid & 7;                 // XCD-affine batch
    const int j   = bid >> 3;                // 0..79: active (qt,s) enumeration
    int g = 0;
    while (j >= 4 * (g + 1) * (g + 2)) g++;  // group g: base 4g(g+1), count 8(g+1)
    const int within = j - 4 * g * (g + 1);
    const int t = within / (g + 1);
    const int s = within - t * (g + 1);
    const int qt = 8 * g + t;
    const int qbase = qt * 64, kstart = s * 512;
    const int kend  = (kstart + 512 < qbase + 64) ? kstart + 512 : qbase + 64;
    const int niter = (kend - kstart) >> 6;  // 1..8

    __shared__ unsigned short Ks[4][64][32];   // 16 KB (chunked by H/32)
    __shared__ unsigned short Vt[128 * 64];    // 16 KB (packed-pair XOR-swizzled transpose)
    __shared__ unsigned short Ps[4][16][64];   //  8 KB (per-wave P^T->A, XOR-swizzled)

    const int tid = threadIdx.x, wave = tid >> 6, lane = tid & 63;
    const int quad = lane >> 4, l16 = lane & 15;
    const size_t base = (size_t)b * T_ * H_;

    // K staging (async) + V regs
    const unsigned short* ksrc = Kg + base + (size_t)(kstart + (lane >> 2)) * H_ + wave * 32 + (lane & 3) * 8;
    #pragma unroll
    for (int p = 0; p < 4; p++) gld16(&Ks[wave][p * 16][0], ksrc + (size_t)p * 16 * H_);
    const unsigned short* vsrc = Vg + base + (size_t)(kstart + wave * 8 + quad * 2) * H_ + l16 * 8;
    u16x8 vr[2][2];
    vr[0][0] = *(const u16x8*)vsrc;             vr[0][1] = *(const u16x8*)(vsrc + H_);
    vr[1][0] = *(const u16x8*)(vsrc + 32 * H_); vr[1][1] = *(const u16x8*)(vsrc + 33 * H_);

    // Q fragments straight from global (loop-invariant)
    bf16x8 qf[4];
    const unsigned short* qp = Qg + base + (size_t)(qbase + wave * 16 + l16) * H_ + quad * 8;
    #pragma unroll
    for (int kk = 0; kk < 4; kk++) qf[kk] = *(const bf16x8*)(qp + kk * 32);

    f32x4 o[8];
    #pragma unroll
    for (int i = 0; i < 8; i++) o[i] = {0.f, 0.f, 0.f, 0.f};
    float m_i = -INFINITY, l_i = 0.f;
    const int swz = (l16 & 7) << 3;
    const int qg = qbase + wave * 16 + l16;    // this lane's q-row

    __syncthreads();                           // Ks(0) landed (barrier drains vmcnt)

    // write Vt(0): packed pairs, XOR swizzle (2-way = free)
    #pragma unroll
    for (int g2 = 0; g2 < 2; g2++) {
        int t0 = wave * 8 + g2 * 32 + quad * 2;
        int t8 = t0 >> 3;
        #pragma unroll
        for (int jj = 0; jj < 8; jj++) {
            int h = l16 * 8 + jj;
            unsigned pk = (unsigned)(unsigned short)vr[g2][0][jj] | ((unsigned)(unsigned short)vr[g2][1][jj] << 16);
            int blk = (t8 ^ (h & 7) ^ ((h >> 3) & 7)) & 7;
            *(unsigned*)&Vt[h * 64 + blk * 8 + (t0 & 7)] = pk;
        }
    }

    for (int kt = 0; ; kt++) {
        const int kbase = kstart + kt * 64;
        // ---- S^T = K Q^T : rows k (quad*4+r within nf*16), col q = l16
        f32x4 st[4];
        #pragma unroll
        for (int nf = 0; nf < 4; nf++) st[nf] = {0.f, 0.f, 0.f, 0.f};
        #pragma unroll
        for (int kk = 0; kk < 4; kk++)
            #pragma unroll
            for (int nf = 0; nf < 4; nf++) {
                bf16x8 kfr = *(bf16x8*)&Ks[kk][nf * 16 + l16][quad * 8];
                st[nf] = MFMA16(kfr, qf[kk], st[nf]);
            }
        // ---- causal mask (diagonal region only; block-uniform branch)
        if (kbase + 64 > qbase) {
            #pragma unroll
            for (int nf = 0; nf < 4; nf++) {
                int kg = kbase + nf * 16 + quad * 4;
                #pragma unroll
                for (int r = 0; r < 4; r++)
                    if (kg + r > qg) st[nf][r] = -INFINITY;
            }
        }
        // ---- online softmax: per-lane q, 15 reg-max + 2 shuffles
        float mx = st[0][0];
        #pragma unroll
        for (int nf = 0; nf < 4; nf++)
            #pragma unroll
            for (int r = 0; r < 4; r++) mx = fmaxf(mx, st[nf][r]);
        mx = fmaxf(mx, __shfl_xor(mx, 16, 64));
        mx = fmaxf(mx, __shfl_xor(mx, 32, 64));
        float mnew = fmaxf(m_i, mx);
        float al = __expf(m_i - mnew);
        m_i = mnew;
        float rs = 0.f;
        #pragma unroll
        for (int nf = 0; nf < 4; nf++)
            #pragma unroll
            for (int r = 0; r < 4; r++) {
                float e = __expf(st[nf][r] - mnew);
                st[nf][r] = e; rs += e;
            }
        rs += __shfl_xor(rs, 16, 64);
        rs += __shfl_xor(rs, 32, 64);
        l_i = al * l_i + rs;
        // ---- P^T -> Ps (A-layout source), packed b64 writes, swizzled
        #pragma unroll
        for (int nf = 0; nf < 4; nf++) {
            uint2 pk = { pk2bf(st[nf][0], st[nf][1]), pk2bf(st[nf][2], st[nf][3]) };
            *(uint2*)&Ps[wave][l16][(nf * 16 + quad * 4) ^ swz] = pk;
        }
        // ---- rescale O (alpha lives at lane l16=q; O rows are quad*4+r)
        float a0 = __shfl(al, quad * 4 + 0, 64), a1 = __shfl(al, quad * 4 + 1, 64);
        float a2 = __shfl(al, quad * 4 + 2, 64), a3 = __shfl(al, quad * 4 + 3, 64);
        #pragma unroll
        for (int i = 0; i < 8; i++) {
            o[i][0] *= a0; o[i][1] *= a1; o[i][2] *= a2; o[i][3] *= a3;
        }
        __syncthreads();   // B: Vt complete, all Ks reads done

        const bool more = (kt + 1 < niter);
        if (more) {        // async prefetch next K; V tile -> regs
            ksrc += 64 * H_;
            #pragma unroll
            for (int p = 0; p < 4; p++) gld16(&Ks[wave][p * 16][0], ksrc + (size_t)p * 16 * H_);
            vsrc += 64 * H_;
            vr[0][0] = *(const u16x8*)vsrc;             vr[0][1] = *(const u16x8*)(vsrc + H_);
            vr[1][0] = *(const u16x8*)(vsrc + 32 * H_); vr[1][1] = *(const u16x8*)(vsrc + 33 * H_);
        }
        // ---- O += P V (overlaps in-flight prefetch)
        bf16x8 pa0 = *(bf16x8*)&Ps[wave][l16][(quad * 8) ^ swz];
        bf16x8 pa1 = *(bf16x8*)&Ps[wave][l16][(32 + quad * 8) ^ swz];
        #pragma unroll
        for (int nf = 0; nf < 8; nf++) {
            int h = nf * 16 + l16;
            int ex = (h & 7) ^ ((h >> 3) & 7);
            bf16x8 v0 = *(bf16x8*)&Vt[h * 64 + ((quad ^ ex) & 7) * 8];
            bf16x8 v1 = *(bf16x8*)&Vt[h * 64 + (((quad + 4) ^ ex) & 7) * 8];
            o[nf] = MFMA16(pa0, v0, o[nf]);
            o[nf] = MFMA16(pa1, v1, o[nf]);
        }
        if (!more) break;
        __syncthreads();   // A: next Ks landed; Vt free to overwrite
        #pragma unroll
        for (int g2 = 0; g2 < 2; g2++) {
            int t0 = wave * 8 + g2 * 32 + quad * 2;
            int t8 = t0 >> 3;
            #pragma unroll
            for (int jj = 0; jj < 8; jj++) {
                int h = l16 * 8 + jj;
                unsigned pk = (unsigned)(unsigned short)vr[g2][0][jj] | ((unsigned)(unsigned short)vr[g2][1][jj] << 16);
                int blk = (t8 ^ (h & 7) ^ ((h >> 3) & 7)) & 7;
                *(unsigned*)&Vt[h * 64 + blk * 8 + (t0 & 7)] = pk;
            }
        }
    }

    // ---- partial epilogue: normalized O (bf16) + (m,l) per row
    const int slot = j * NB + b;               // == (Pq + s)*NB + b
    float lq[4];
    #pragma unroll
    for (int r = 0; r < 4; r++) lq[r] = __shfl(l_i, quad * 4 + r, 64);
    const size_t obase = (size_t)slot * 64 * 128;
    #pragma unroll
    for (int r = 0; r < 4; r++) {
        float invl = 1.0f / lq[r];
        #pragma unroll
        for (int nf = 0; nf < 8; nf++)
            Ob[obase + (size_t)(wave * 16 + quad * 4 + r) * 128 + nf * 16 + l16] = f2bf(o[nf][r] * invl);
    }
    if (lane < 16) {
        int ridx = slot * 64 + wave * 16 + l16;
        Ml[ridx * 2]     = m_i;
        Ml[ridx * 2 + 1] = l_i;
    }
}

// ---------- kernel 4: merge splits (log-sum-exp recombination, ns <= 4) ----------
__global__ __launch_bounds__(256) void merge(const unsigned short* __restrict__ Ob,
                                             const float* __restrict__ Ml,
                                             float* __restrict__ out) {
    const int qt = blockIdx.x, b = blockIdx.y;
    const int g = qt >> 3;
    const int Pq = 4 * g * (g + 1) + (qt & 7) * (g + 1);
    const int ns = g + 1;                    // 1..4
    const int tid = threadIdx.x;
    const int row = tid >> 2, c0 = (tid & 3) * 32;

    float mv[4], lv[4], mg = -INFINITY;
    for (int s2 = 0; s2 < ns; s2++) {
        int slot = (Pq + s2) * NB + b;
        mv[s2] = Ml[(slot * 64 + row) * 2];
        lv[s2] = Ml[(slot * 64 + row) * 2 + 1];
        mg = fmaxf(mg, mv[s2]);
    }
    float L = 0.f, w[4];
    for (int s2 = 0; s2 < ns; s2++) { w[s2] = lv[s2] * __expf(mv[s2] - mg); L += w[s2]; }
    float inv = 1.0f / L;

    float accv[32];
    #pragma unroll
    for (int i = 0; i < 32; i++) accv[i] = 0.f;
    for (int s2 = 0; s2 < ns; s2++) {
        int slot = (Pq + s2) * NB + b;
        const unsigned short* op = Ob + ((size_t)(slot * 64 + row)) * 128 + c0;
        #pragma unroll
        for (int cc = 0; cc < 4; cc++) {
            u16x8 v = *(const u16x8*)(op + cc * 8);
            #pragma unroll
            for (int jj = 0; jj < 8; jj++) accv[cc * 8 + jj] += w[s2] * bf2f(v[jj]);
        }
    }
    float* od = out + ((size_t)(b * T_ + qt * 64 + row)) * 128 + c0;
    #pragma unroll
    for (int cc = 0; cc < 8; cc++) {
        float4 w4 = { accv[cc*4] * inv, accv[cc*4+1] * inv, accv[cc*4+2] * inv, accv[cc*4+3] * inv };
        *(float4*)(od + cc * 4) = w4;
    }
}

extern "C" void kernel_launch(void* const* d_in, const int* in_sizes, int n_in,
                              void* d_out, int out_size, void* d_ws, size_t ws_size,
                              hipStream_t stream) {
    const float* x  = (const float*)d_in[0];
    const float* Wq = (const float*)d_in[1];
    const float* Wk = (const float*)d_in[2];
    const float* Wv = (const float*)d_in[3];

    char* ws = (char*)d_ws;
    unsigned short* Wb = (unsigned short*)ws;                          // 0.75 MB @ 0
    unsigned short* Q  = (unsigned short*)(ws + (size_t) 1 * (1u << 20)); // 4 MB
    unsigned short* K  = (unsigned short*)(ws + (size_t) 5 * (1u << 20));
    unsigned short* V  = (unsigned short*)(ws + (size_t) 9 * (1u << 20));
    unsigned short* Ob = (unsigned short*)(ws + (size_t)13 * (1u << 20)); // 10.5 MB (640 slots)
    float*          Ml = (float*)(ws + (size_t)32 * (1u << 20));          // 0.33 MB
    float* out = (float*)d_out;

    hipLaunchKernelGGL(wconv, dim3(192), dim3(256), 0, stream, Wq, Wk, Wv, Wb);
    hipLaunchKernelGGL(proj,  dim3(512), dim3(256), 0, stream, x, Wb, Q, K, V);
    hipLaunchKernelGGL(attn,  dim3(640), dim3(256), 0, stream, Q, K, V, Ob, Ml);
    hipLaunchKernelGGL(merge, dim3(32, NB), dim3(256), 0, stream, Ob, Ml, out);
}

// Round 10
// 152.681 us; speedup vs baseline: 1.1476x; 1.1476x over previous
//
#include <hip/hip_runtime.h>
#include <hip/hip_bf16.h>
#include <math.h>

#define T_ 2048
#define C_ 1024
#define H_ 128
#define NB 8
#define WN 131072                 // 128*1024 per weight
#define SC 0.08838834764831845f   // 1/sqrt(128)

typedef __attribute__((ext_vector_type(8))) short bf16x8;
typedef __attribute__((ext_vector_type(8))) unsigned short u16x8;
typedef __attribute__((ext_vector_type(4))) float f32x4;

#define MFMA16(a,b,c) __builtin_amdgcn_mfma_f32_16x16x32_bf16((a),(b),(c),0,0,0)

__device__ __forceinline__ unsigned short f2bf(float f) {
    union { float f; unsigned u; } v; v.f = f;
    unsigned r = v.u + 0x7fffu + ((v.u >> 16) & 1u);
    return (unsigned short)(r >> 16);
}
__device__ __forceinline__ float bf2f(unsigned short u) {
    union { unsigned u; float f; } v; v.u = ((unsigned)u) << 16; return v.f;
}
__device__ __forceinline__ unsigned pk2bf(float a, float b) {
    __hip_bfloat162 h = __float22bfloat162_rn(float2{a, b});
    union { __hip_bfloat162 h; unsigned u; } v; v.h = h; return v.u;
}
// async global->LDS, 16B per lane; lds dest = uniform base + laneid*16
__device__ __forceinline__ void gld16(void* lds, const void* g) {
    __builtin_amdgcn_global_load_lds(
        (const __attribute__((address_space(1))) unsigned*)g,
        (__attribute__((address_space(3))) unsigned*)lds, 16, 0, 0);
}

// ---------- kernel 1: W fp32 -> bf16 (Wq pre-scaled by 1/sqrt(H)) ----------
__global__ __launch_bounds__(256) void wconv(const float* __restrict__ Wq,
                                             const float* __restrict__ Wk,
                                             const float* __restrict__ Wv,
                                             unsigned short* __restrict__ Wb) {
    int e = (blockIdx.x * 256 + threadIdx.x) * 8;       // < 393216
    int which = e >> 17;
    int off = e & (WN - 1);
    const float* src = (which == 0) ? Wq : (which == 1 ? Wk : Wv);
    float s = (which == 0) ? SC : 1.0f;
    const float4* p = (const float4*)(src + off);
    float4 a = p[0], b = p[1];
    uint4 o = { pk2bf(a.x * s, a.y * s), pk2bf(a.z * s, a.w * s),
                pk2bf(b.x * s, b.y * s), pk2bf(b.z * s, b.w * s) };
    *(uint4*)(Wb + e) = o;
}

// ---------- kernel 2: fused QKV projection (v4 + XCD-paired N-splits) ----------
// R8's proven v4 (64x192, BK=64, counted vmcnt(4), depth-2 x prefetch) with ONE
// change: bid remap so BOTH N-split blocks of an M-tile land on the SAME XCD
// (bids 16g+x and 16g+8+x are both == x mod 8 -> same XCD under round-robin).
// The pair is co-resident + iteration-synced, so the second block's x stripe
// hits that XCD's L2 -> x read from HBM once (FETCH ~67 -> ~36 MB predicted).
__global__ __launch_bounds__(256, 2) void proj(const float* __restrict__ x,
                                               const unsigned short* __restrict__ Wb,
                                               unsigned short* __restrict__ Q,
                                               unsigned short* __restrict__ K,
                                               unsigned short* __restrict__ V) {
    __shared__ unsigned short Xs[2][64][64];    // 16 KB, swizzled slots
    __shared__ unsigned short Ws[2][192][64];   // 48 KB, swizzled slots

    const int tid  = threadIdx.x;
    const int wave = tid >> 6, lane = tid & 63;
    const int quad = lane >> 4, l16 = lane & 15;
    const int wm   = wave >> 1, wn = wave & 1;
    const int bid  = blockIdx.x;
    const int m0   = (((bid >> 4) << 3) | (bid & 7)) * 64;   // M-tile 8g+x
    const int n0   = ((bid >> 3) & 1) * 192;                 // N-split on same XCD pair

    f32x4 acc[2][6];
    #pragma unroll
    for (int i = 0; i < 2; i++)
        #pragma unroll
        for (int j = 0; j < 6; j++) acc[i][j] = {0.f, 0.f, 0.f, 0.f};

    const int xrow = tid >> 2, xcg = tid & 3;
    const float* xg = x + (size_t)(m0 + xrow) * C_ + xcg * 16;
    const int xk = xrow & 7;                                  // Xs swizzle key
    const int key = l16 & 7;                                  // read-side swizzle key
    const unsigned short* wg = Wb + (size_t)(n0 + wave * 48 + (lane >> 3)) * C_
                               + (size_t)(((lane & 7) ^ (lane >> 3)) * 8);

    float4 xA[4], xB[4];

    #define WISSUE(buf, kc) do {                                                  \
        _Pragma("unroll")                                                         \
        for (int i = 0; i < 6; i++)                                               \
            gld16(&Ws[buf][wave * 48 + i * 8][0], wg + (size_t)i * 8 * C_ + (kc));\
    } while (0)

    #define XLOAD(dst, kc) do {                                                   \
        const float* xp = xg + (kc);                                              \
        dst[0] = *(const float4*)xp;        dst[1] = *(const float4*)(xp + 4);    \
        dst[2] = *(const float4*)(xp + 8);  dst[3] = *(const float4*)(xp + 12);   \
    } while (0)

    #define XWR(buf, src) do {                                                    \
        uint4 u0 = { pk2bf(src[0].x, src[0].y), pk2bf(src[0].z, src[0].w),        \
                     pk2bf(src[1].x, src[1].y), pk2bf(src[1].z, src[1].w) };      \
        uint4 u1 = { pk2bf(src[2].x, src[2].y), pk2bf(src[2].z, src[2].w),        \
                     pk2bf(src[3].x, src[3].y), pk2bf(src[3].z, src[3].w) };      \
        *(uint4*)&Xs[buf][xrow][((2 * xcg)     ^ xk) * 8] = u0;                   \
        *(uint4*)&Xs[buf][xrow][((2 * xcg + 1) ^ xk) * 8] = u1;                   \
    } while (0)

    #define COMPUTE(buf) do {                                                     \
        bf16x8 af[2][2];                                                          \
        _Pragma("unroll")                                                         \
        for (int kk = 0; kk < 2; kk++)                                            \
            _Pragma("unroll")                                                     \
            for (int mf = 0; mf < 2; mf++)                                        \
                af[mf][kk] = *(bf16x8*)&Xs[buf][wm * 32 + mf * 16 + l16]          \
                                          [((kk * 4 + quad) ^ key) * 8];          \
        _Pragma("unroll")                                                         \
        for (int kk = 0; kk < 2; kk++)                                            \
            _Pragma("unroll")                                                     \
            for (int nf = 0; nf < 6; nf++) {                                      \
                bf16x8 bq = *(bf16x8*)&Ws[buf][wn * 96 + nf * 16 + l16]           \
                                         [((kk * 4 + quad) ^ key) * 8];           \
                acc[0][nf] = MFMA16(af[0][kk], bq, acc[0][nf]);                   \
                acc[1][nf] = MFMA16(af[1][kk], bq, acc[1][nf]);                   \
            }                                                                     \
    } while (0)

    #define BAR4 do {                                                             \
        asm volatile("s_waitcnt vmcnt(4) lgkmcnt(0)" ::: "memory");               \
        __builtin_amdgcn_s_barrier();                                             \
        __builtin_amdgcn_sched_barrier(0);                                        \
    } while (0)
    #define BAR0 do {                                                             \
        asm volatile("s_waitcnt vmcnt(0) lgkmcnt(0)" ::: "memory");               \
        __builtin_amdgcn_s_barrier();                                             \
        __builtin_amdgcn_sched_barrier(0);                                        \
    } while (0)
    #define PIN __builtin_amdgcn_sched_barrier(0)

    // prologue: x(0), W(0), x(1); Xs[0] <- x(0)
    XLOAD(xA, 0);
    WISSUE(0, 0);
    PIN;
    XLOAD(xB, 64);
    XWR(0, xA);                       // auto vmcnt wait on xA

    // iters 0..13 as 7 pairs (parity -> compile-time reg-set/buf indices)
    for (int t = 0; t < 7; t++) {
        BAR4;                         // W(2t) landed; x(2t+1) still flying
        WISSUE(1, (2 * t + 1) * 64);
        PIN;                          // keep W older than x (vmcnt arithmetic)
        XLOAD(xA, (2 * t + 2) * 64);
        COMPUTE(0);
        XWR(1, xB);                   // Xs[1] <- x(2t+1)
        BAR4;
        WISSUE(0, (2 * t + 2) * 64);
        PIN;
        XLOAD(xB, (2 * t + 3) * 64);
        COMPUTE(1);
        XWR(0, xA);                   // Xs[0] <- x(2t+2)
    }
    // it=14 (buf 0): last W issue, no more x loads
    BAR4;
    WISSUE(1, 15 * 64);
    COMPUTE(0);
    XWR(1, xB);                       // Xs[1] <- x(15)
    // it=15 (buf 1): full drain
    BAR0;
    COMPUTE(1);

    #undef WISSUE
    #undef XLOAD
    #undef XWR
    #undef COMPUTE
    #undef BAR4
    #undef BAR0
    #undef PIN

    #pragma unroll
    for (int nf = 0; nf < 6; nf++) {
        int nb = n0 + wn * 96 + nf * 16;
        int which = nb >> 7;                   // frag-uniform (16-col frag never straddles)
        unsigned short* dst = (which == 0) ? Q : (which == 1 ? K : V);
        int c = (nb & 127) + l16;
        #pragma unroll
        for (int mf = 0; mf < 2; mf++)
            #pragma unroll
            for (int r = 0; r < 4; r++)
                dst[(size_t)(m0 + wm * 32 + mf * 16 + quad * 4 + r) * H_ + c] = f2bf(acc[mf][nf][r]);
    }
}

// ---------- kernel 3: split-K flash causal attention (v6: split width 512, unchanged) ----------
__global__ __launch_bounds__(256, 3) void attn(const unsigned short* __restrict__ Qg,
                                               const unsigned short* __restrict__ Kg,
                                               const unsigned short* __restrict__ Vg,
                                               unsigned short* __restrict__ Ob,
                                               float* __restrict__ Ml) {
    const int bid = blockIdx.x;
    const int b   = bid & 7;                 // XCD-affine batch
    const int j   = bid >> 3;                // 0..79: active (qt,s) enumeration
    int g = 0;
    while (j >= 4 * (g + 1) * (g + 2)) g++;  // group g: base 4g(g+1), count 8(g+1)
    const int within = j - 4 * g * (g + 1);
    const int t = within / (g + 1);
    const int s = within - t * (g + 1);
    const int qt = 8 * g + t;
    const int qbase = qt * 64, kstart = s * 512;
    const int kend  = (kstart + 512 < qbase + 64) ? kstart + 512 : qbase + 64;
    const int niter = (kend - kstart) >> 6;  // 1..8

    __shared__ unsigned short Ks[4][64][32];   // 16 KB (chunked by H/32)
    __shared__ unsigned short Vt[128 * 64];    // 16 KB (packed-pair XOR-swizzled transpose)
    __shared__ unsigned short Ps[4][16][64];   //  8 KB (per-wave P^T->A, XOR-swizzled)

    const int tid = threadIdx.x, wave = tid >> 6, lane = tid & 63;
    const int quad = lane >> 4, l16 = lane & 15;
    const size_t base = (size_t)b * T_ * H_;

    // K staging (async) + V regs
    const unsigned short* ksrc = Kg + base + (size_t)(kstart + (lane >> 2)) * H_ + wave * 32 + (lane & 3) * 8;
    #pragma unroll
    for (int p = 0; p < 4; p++) gld16(&Ks[wave][p * 16][0], ksrc + (size_t)p * 16 * H_);
    const unsigned short* vsrc = Vg + base + (size_t)(kstart + wave * 8 + quad * 2) * H_ + l16 * 8;
    u16x8 vr[2][2];
    vr[0][0] = *(const u16x8*)vsrc;             vr[0][1] = *(const u16x8*)(vsrc + H_);
    vr[1][0] = *(const u16x8*)(vsrc + 32 * H_); vr[1][1] = *(const u16x8*)(vsrc + 33 * H_);

    // Q fragments straight from global (loop-invariant)
    bf16x8 qf[4];
    const unsigned short* qp = Qg + base + (size_t)(qbase + wave * 16 + l16) * H_ + quad * 8;
    #pragma unroll
    for (int kk = 0; kk < 4; kk++) qf[kk] = *(const bf16x8*)(qp + kk * 32);

    f32x4 o[8];
    #pragma unroll
    for (int i = 0; i < 8; i++) o[i] = {0.f, 0.f, 0.f, 0.f};
    float m_i = -INFINITY, l_i = 0.f;
    const int swz = (l16 & 7) << 3;
    const int qg = qbase + wave * 16 + l16;    // this lane's q-row

    __syncthreads();                           // Ks(0) landed (barrier drains vmcnt)

    // write Vt(0): packed pairs, XOR swizzle (2-way = free)
    #pragma unroll
    for (int g2 = 0; g2 < 2; g2++) {
        int t0 = wave * 8 + g2 * 32 + quad * 2;
        int t8 = t0 >> 3;
        #pragma unroll
        for (int jj = 0; jj < 8; jj++) {
            int h = l16 * 8 + jj;
            unsigned pk = (unsigned)(unsigned short)vr[g2][0][jj] | ((unsigned)(unsigned short)vr[g2][1][jj] << 16);
            int blk = (t8 ^ (h & 7) ^ ((h >> 3) & 7)) & 7;
            *(unsigned*)&Vt[h * 64 + blk * 8 + (t0 & 7)] = pk;
        }
    }

    for (int kt = 0; ; kt++) {
        const int kbase = kstart + kt * 64;
        // ---- S^T = K Q^T : rows k (quad*4+r within nf*16), col q = l16
        f32x4 st[4];
        #pragma unroll
        for (int nf = 0; nf < 4; nf++) st[nf] = {0.f, 0.f, 0.f, 0.f};
        #pragma unroll
        for (int kk = 0; kk < 4; kk++)
            #pragma unroll
            for (int nf = 0; nf < 4; nf++) {
                bf16x8 kfr = *(bf16x8*)&Ks[kk][nf * 16 + l16][quad * 8];
                st[nf] = MFMA16(kfr, qf[kk], st[nf]);
            }
        // ---- causal mask (diagonal region only; block-uniform branch)
        if (kbase + 64 > qbase) {
            #pragma unroll
            for (int nf = 0; nf < 4; nf++) {
                int kg = kbase + nf * 16 + quad * 4;
                #pragma unroll
                for (int r = 0; r < 4; r++)
                    if (kg + r > qg) st[nf][r] = -INFINITY;
            }
        }
        // ---- online softmax: per-lane q, 15 reg-max + 2 shuffles
        float mx = st[0][0];
        #pragma unroll
        for (int nf = 0; nf < 4; nf++)
            #pragma unroll
            for (int r = 0; r < 4; r++) mx = fmaxf(mx, st[nf][r]);
        mx = fmaxf(mx, __shfl_xor(mx, 16, 64));
        mx = fmaxf(mx, __shfl_xor(mx, 32, 64));
        float mnew = fmaxf(m_i, mx);
        float al = __expf(m_i - mnew);
        m_i = mnew;
        float rs = 0.f;
        #pragma unroll
        for (int nf = 0; nf < 4; nf++)
            #pragma unroll
            for (int r = 0; r < 4; r++) {
                float e = __expf(st[nf][r] - mnew);
                st[nf][r] = e; rs += e;
            }
        rs += __shfl_xor(rs, 16, 64);
        rs += __shfl_xor(rs, 32, 64);
        l_i = al * l_i + rs;
        // ---- P^T -> Ps (A-layout source), packed b64 writes, swizzled
        #pragma unroll
        for (int nf = 0; nf < 4; nf++) {
            uint2 pk = { pk2bf(st[nf][0], st[nf][1]), pk2bf(st[nf][2], st[nf][3]) };
            *(uint2*)&Ps[wave][l16][(nf * 16 + quad * 4) ^ swz] = pk;
        }
        // ---- rescale O (alpha lives at lane l16=q; O rows are quad*4+r)
        float a0 = __shfl(al, quad * 4 + 0, 64), a1 = __shfl(al, quad * 4 + 1, 64);
        float a2 = __shfl(al, quad * 4 + 2, 64), a3 = __shfl(al, quad * 4 + 3, 64);
        #pragma unroll
        for (int i = 0; i < 8; i++) {
            o[i][0] *= a0; o[i][1] *= a1; o[i][2] *= a2; o[i][3] *= a3;
        }
        __syncthreads();   // B: Vt complete, all Ks reads done

        const bool more = (kt + 1 < niter);
        if (more) {        // async prefetch next K; V tile -> regs
            ksrc += 64 * H_;
            #pragma unroll
            for (int p = 0; p < 4; p++) gld16(&Ks[wave][p * 16][0], ksrc + (size_t)p * 16 * H_);
            vsrc += 64 * H_;
            vr[0][0] = *(const u16x8*)vsrc;             vr[0][1] = *(const u16x8*)(vsrc + H_);
            vr[1][0] = *(const u16x8*)(vsrc + 32 * H_); vr[1][1] = *(const u16x8*)(vsrc + 33 * H_);
        }
        // ---- O += P V (overlaps in-flight prefetch)
        bf16x8 pa0 = *(bf16x8*)&Ps[wave][l16][(quad * 8) ^ swz];
        bf16x8 pa1 = *(bf16x8*)&Ps[wave][l16][(32 + quad * 8) ^ swz];
        #pragma unroll
        for (int nf = 0; nf < 8; nf++) {
            int h = nf * 16 + l16;
            int ex = (h & 7) ^ ((h >> 3) & 7);
            bf16x8 v0 = *(bf16x8*)&Vt[h * 64 + ((quad ^ ex) & 7) * 8];
            bf16x8 v1 = *(bf16x8*)&Vt[h * 64 + (((quad + 4) ^ ex) & 7) * 8];
            o[nf] = MFMA16(pa0, v0, o[nf]);
            o[nf] = MFMA16(pa1, v1, o[nf]);
        }
        if (!more) break;
        __syncthreads();   // A: next Ks landed; Vt free to overwrite
        #pragma unroll
        for (int g2 = 0; g2 < 2; g2++) {
            int t0 = wave * 8 + g2 * 32 + quad * 2;
            int t8 = t0 >> 3;
            #pragma unroll
            for (int jj = 0; jj < 8; jj++) {
                int h = l16 * 8 + jj;
                unsigned pk = (unsigned)(unsigned short)vr[g2][0][jj] | ((unsigned)(unsigned short)vr[g2][1][jj] << 16);
                int blk = (t8 ^ (h & 7) ^ ((h >> 3) & 7)) & 7;
                *(unsigned*)&Vt[h * 64 + blk * 8 + (t0 & 7)] = pk;
            }
        }
    }

    // ---- partial epilogue: normalized O (bf16) + (m,l) per row
    const int slot = j * NB + b;               // == (Pq + s)*NB + b
    float lq[4];
    #pragma unroll
    for (int r = 0; r < 4; r++) lq[r] = __shfl(l_i, quad * 4 + r, 64);
    const size_t obase = (size_t)slot * 64 * 128;
    #pragma unroll
    for (int r = 0; r < 4; r++) {
        float invl = 1.0f / lq[r];
        #pragma unroll
        for (int nf = 0; nf < 8; nf++)
            Ob[obase + (size_t)(wave * 16 + quad * 4 + r) * 128 + nf * 16 + l16] = f2bf(o[nf][r] * invl);
    }
    if (lane < 16) {
        int ridx = slot * 64 + wave * 16 + l16;
        Ml[ridx * 2]     = m_i;
        Ml[ridx * 2 + 1] = l_i;
    }
}

// ---------- kernel 4: merge splits (log-sum-exp recombination, ns <= 4) ----------
__global__ __launch_bounds__(256) void merge(const unsigned short* __restrict__ Ob,
                                             const float* __restrict__ Ml,
                                             float* __restrict__ out) {
    const int qt = blockIdx.x, b = blockIdx.y;
    const int g = qt >> 3;
    const int Pq = 4 * g * (g + 1) + (qt & 7) * (g + 1);
    const int ns = g + 1;                    // 1..4
    const int tid = threadIdx.x;
    const int row = tid >> 2, c0 = (tid & 3) * 32;

    float mv[4], lv[4], mg = -INFINITY;
    for (int s2 = 0; s2 < ns; s2++) {
        int slot = (Pq + s2) * NB + b;
        mv[s2] = Ml[(slot * 64 + row) * 2];
        lv[s2] = Ml[(slot * 64 + row) * 2 + 1];
        mg = fmaxf(mg, mv[s2]);
    }
    float L = 0.f, w[4];
    for (int s2 = 0; s2 < ns; s2++) { w[s2] = lv[s2] * __expf(mv[s2] - mg); L += w[s2]; }
    float inv = 1.0f / L;

    float accv[32];
    #pragma unroll
    for (int i = 0; i < 32; i++) accv[i] = 0.f;
    for (int s2 = 0; s2 < ns; s2++) {
        int slot = (Pq + s2) * NB + b;
        const unsigned short* op = Ob + ((size_t)(slot * 64 + row)) * 128 + c0;
        #pragma unroll
        for (int cc = 0; cc < 4; cc++) {
            u16x8 v = *(const u16x8*)(op + cc * 8);
            #pragma unroll
            for (int jj = 0; jj < 8; jj++) accv[cc * 8 + jj] += w[s2] * bf2f(v[jj]);
        }
    }
    float* od = out + ((size_t)(b * T_ + qt * 64 + row)) * 128 + c0;
    #pragma unroll
    for (int cc = 0; cc < 8; cc++) {
        float4 w4 = { accv[cc*4] * inv, accv[cc*4+1] * inv, accv[cc*4+2] * inv, accv[cc*4+3] * inv };
        *(float4*)(od + cc * 4) = w4;
    }
}

extern "C" void kernel_launch(void* const* d_in, const int* in_sizes, int n_in,
                              void* d_out, int out_size, void* d_ws, size_t ws_size,
                              hipStream_t stream) {
    const float* x  = (const float*)d_in[0];
    const float* Wq = (const float*)d_in[1];
    const float* Wk = (const float*)d_in[2];
    const float* Wv = (const float*)d_in[3];

    char* ws = (char*)d_ws;
    unsigned short* Wb = (unsigned short*)ws;                          // 0.75 MB @ 0
    unsigned short* Q  = (unsigned short*)(ws + (size_t) 1 * (1u << 20)); // 4 MB
    unsigned short* K  = (unsigned short*)(ws + (size_t) 5 * (1u << 20));
    unsigned short* V  = (unsigned short*)(ws + (size_t) 9 * (1u << 20));
    unsigned short* Ob = (unsigned short*)(ws + (size_t)13 * (1u << 20)); // 10.5 MB (640 slots)
    float*          Ml = (float*)(ws + (size_t)32 * (1u << 20));          // 0.33 MB
    float* out = (float*)d_out;

    hipLaunchKernelGGL(wconv, dim3(192), dim3(256), 0, stream, Wq, Wk, Wv, Wb);
    hipLaunchKernelGGL(proj,  dim3(512), dim3(256), 0, stream, x, Wb, Q, K, V);
    hipLaunchKernelGGL(attn,  dim3(640), dim3(256), 0, stream, Q, K, V, Ob, Ml);
    hipLaunchKernelGGL(merge, dim3(32, NB), dim3(256), 0, stream, Ob, Ml, out);
}